// Round 1
// baseline (423.084 us; speedup 1.0000x reference)
//
#include <hip/hip_runtime.h>
#include <math.h>

// Problem dims (fixed)
constexpr int H_ = 1024;
constexpr int I_ = 2816;
constexpr int E_ = 8;
constexpr int T_ = 1024;   // S*B tokens

typedef __bf16 bf16x8 __attribute__((ext_vector_type(8)));
typedef float f32x4 __attribute__((ext_vector_type(4)));

__device__ __forceinline__ ushort f2bf(float f) {
    uint32_t u = __float_as_uint(f);
    u += 0x7fff + ((u >> 16) & 1);   // round-to-nearest-even
    return (ushort)(u >> 16);
}
__device__ __forceinline__ uint pack2(float lo, float hi) {
    return (uint)f2bf(lo) | ((uint)f2bf(hi) << 16);
}
__device__ __forceinline__ bf16x8 cvt8(float4 a, float4 b) {
    union { uint u[4]; bf16x8 v; } r;
    r.u[0] = pack2(a.x, a.y); r.u[1] = pack2(a.z, a.w);
    r.u[2] = pack2(b.x, b.y); r.u[3] = pack2(b.z, b.w);
    return r.v;
}
__device__ __forceinline__ bf16x8 as_bf16x8(uint4 v) {
    union { uint4 u; bf16x8 b; } c; c.u = v; return c.b;
}

// ws layout: int counts[8]; int tlist[8*1024]; ushort xbf[1024*1024]; ushort act[1024*2816]

__global__ __launch_bounds__(64) void router_kernel(const float* __restrict__ hidden,
                                                    const float* __restrict__ rw,
                                                    int* __restrict__ counts,
                                                    int* __restrict__ tlist,
                                                    ushort* __restrict__ xbf) {
    const int t = blockIdx.x;
    const int lane = threadIdx.x;
    const float* x = hidden + (size_t)t * H_ + lane * 16;
    float4 v[4];
#pragma unroll
    for (int j = 0; j < 4; j++) v[j] = ((const float4*)x)[j];
    uint2* xb = (uint2*)(xbf + (size_t)t * H_ + lane * 16);
#pragma unroll
    for (int j = 0; j < 4; j++) xb[j] = make_uint2(pack2(v[j].x, v[j].y), pack2(v[j].z, v[j].w));
    float acc[E_];
#pragma unroll
    for (int e = 0; e < E_; e++) {
        const float4* r = (const float4*)(rw + e * H_ + lane * 16);
        float a = 0.f;
#pragma unroll
        for (int j = 0; j < 4; j++) {
            float4 rv = r[j];
            a += v[j].x * rv.x + v[j].y * rv.y + v[j].z * rv.z + v[j].w * rv.w;
        }
        acc[e] = a;
    }
#pragma unroll
    for (int e = 0; e < E_; e++) {
#pragma unroll
        for (int off = 32; off >= 1; off >>= 1)
            acc[e] += __shfl_xor(acc[e], off, 64);
    }
    if (lane == 0) {
        int best = 0;
        float bv = acc[0];
#pragma unroll
        for (int e = 1; e < E_; e++) {
            if (acc[e] > bv) { bv = acc[e]; best = e; }  // strict > : first max wins
        }
        int pos = atomicAdd(&counts[best], 1);
        tlist[best * T_ + pos] = t;
    }
}

// Phase A: per expert e, 32 I-rows per block, M=256 tokens (64/wave), barrier-free
// register-direct streaming: fragments loaded straight from global, fp32 weights
// packed to bf16 in-register. No LDS staging (weights have zero cross-block reuse;
// intra-block 4-wave redundancy is absorbed by L2).
__global__ __launch_bounds__(256, 2) void gateup_kernel(const ushort* __restrict__ xbf,
                                                        const float* __restrict__ gate_w,
                                                        const float* __restrict__ up_w,
                                                        const int* __restrict__ counts,
                                                        const int* __restrict__ tlist,
                                                        ushort* __restrict__ act) {
    const int e  = blockIdx.y;
    const int i0 = blockIdx.x * 32;
    const int cnt = counts[e];
    const int tid = threadIdx.x;
    const int wv = tid >> 6, lane = tid & 63, quad = lane >> 4, l15 = lane & 15;

    __shared__ int toks[256];

    // per-lane fragment base pointers: row = l15 (+16 for nj=1), k-chunk = quad*8
    const float* gw0 = gate_w + ((size_t)e * I_ + i0 + l15) * H_ + quad * 8;
    const float* gw1 = gw0 + (size_t)16 * H_;
    const float* uw0 = up_w   + ((size_t)e * I_ + i0 + l15) * H_ + quad * 8;
    const float* uw1 = uw0 + (size_t)16 * H_;

    for (int toff = 0; toff < cnt; toff += 256) {
        __syncthreads();
        { int p = toff + tid; toks[tid] = (p < cnt) ? tlist[e * T_ + p] : -1; }
        __syncthreads();
        if (cnt - toff <= wv * 64) continue;   // wave-uniform: this wave has no valid tokens

        int tka[4];
        const ushort* xa[4];
#pragma unroll
        for (int mi = 0; mi < 4; mi++) {
            tka[mi] = toks[wv * 64 + mi * 16 + l15];
            xa[mi] = xbf + (size_t)(tka[mi] < 0 ? 0 : tka[mi]) * H_ + quad * 8;
        }

        f32x4 accg[4][2], accu[4][2];
#pragma unroll
        for (int mi = 0; mi < 4; mi++)
#pragma unroll
            for (int nj = 0; nj < 2; nj++) {
                accg[mi][nj] = (f32x4){0.f, 0.f, 0.f, 0.f};
                accu[mi][nj] = (f32x4){0.f, 0.f, 0.f, 0.f};
            }

        uint4 a0[4], a1[4];
        float4 g0[2][2], g1[2][2], u0[2][2], u1[2][2];

#define GU_LOAD(A, G, U, kk) do {                                                   \
        const int k_ = (kk);                                                        \
        _Pragma("unroll")                                                           \
        for (int mi = 0; mi < 4; mi++)                                              \
            A[mi] = (tka[mi] >= 0) ? *(const uint4*)(xa[mi] + k_)                   \
                                   : make_uint4(0u, 0u, 0u, 0u);                    \
        G[0][0] = *(const float4*)(gw0 + k_); G[0][1] = *(const float4*)(gw0 + k_ + 4); \
        G[1][0] = *(const float4*)(gw1 + k_); G[1][1] = *(const float4*)(gw1 + k_ + 4); \
        U[0][0] = *(const float4*)(uw0 + k_); U[0][1] = *(const float4*)(uw0 + k_ + 4); \
        U[1][0] = *(const float4*)(uw1 + k_); U[1][1] = *(const float4*)(uw1 + k_ + 4); \
    } while (0)

#define GU_MFMA(A, G, U) do {                                                       \
        bf16x8 bg[2], bu[2];                                                        \
        _Pragma("unroll")                                                           \
        for (int nj = 0; nj < 2; nj++) {                                            \
            bg[nj] = cvt8(G[nj][0], G[nj][1]);                                      \
            bu[nj] = cvt8(U[nj][0], U[nj][1]);                                      \
        }                                                                           \
        _Pragma("unroll")                                                           \
        for (int mi = 0; mi < 4; mi++) {                                            \
            bf16x8 aa = as_bf16x8(A[mi]);                                           \
            _Pragma("unroll")                                                       \
            for (int nj = 0; nj < 2; nj++) {                                        \
                accg[mi][nj] = __builtin_amdgcn_mfma_f32_16x16x32_bf16(aa, bg[nj], accg[mi][nj], 0, 0, 0); \
                accu[mi][nj] = __builtin_amdgcn_mfma_f32_16x16x32_bf16(aa, bu[nj], accu[mi][nj], 0, 0, 0); \
            }                                                                       \
        }                                                                           \
    } while (0)

        GU_LOAD(a0, g0, u0, 0);
#pragma unroll 1
        for (int k0 = 0; k0 < H_; k0 += 64) {
            GU_LOAD(a1, g1, u1, k0 + 32);
            GU_MFMA(a0, g0, u0);
            if (k0 + 64 < H_) GU_LOAD(a0, g0, u0, k0 + 64);
            GU_MFMA(a1, g1, u1);
        }
#undef GU_LOAD
#undef GU_MFMA

#pragma unroll
        for (int mi = 0; mi < 4; mi++)
#pragma unroll
            for (int r = 0; r < 4; r++) {
                int tok = toks[wv * 64 + mi * 16 + quad * 4 + r];
                if (tok < 0) continue;
#pragma unroll
                for (int nj = 0; nj < 2; nj++) {
                    float g = accg[mi][nj][r], u = accu[mi][nj][r];
                    float s = g / (1.f + __expf(-g)) * u;
                    act[(size_t)tok * I_ + i0 + nj * 16 + l15] = f2bf(s);
                }
            }
    }
}

// Phase B: per expert e, 16 H-rows per block (grid 64*8=512 so all CUs are fed),
// M=256 tokens (64/wave), K=I=2816, same barrier-free register streaming.
__global__ __launch_bounds__(256, 2) void down_kernel(const ushort* __restrict__ act,
                                                      const float* __restrict__ down_w,
                                                      const int* __restrict__ counts,
                                                      const int* __restrict__ tlist,
                                                      float* __restrict__ out) {
    const int e  = blockIdx.y;
    const int h0 = blockIdx.x * 16;
    const int cnt = counts[e];
    const int tid = threadIdx.x;
    const int wv = tid >> 6, lane = tid & 63, quad = lane >> 4, l15 = lane & 15;

    __shared__ int toks[256];
    const float* dw = down_w + ((size_t)e * H_ + h0 + l15) * I_ + quad * 8;

    for (int toff = 0; toff < cnt; toff += 256) {
        __syncthreads();
        { int p = toff + tid; toks[tid] = (p < cnt) ? tlist[e * T_ + p] : -1; }
        __syncthreads();
        if (cnt - toff <= wv * 64) continue;

        int tka[4];
        const ushort* xa[4];
#pragma unroll
        for (int mi = 0; mi < 4; mi++) {
            tka[mi] = toks[wv * 64 + mi * 16 + l15];
            xa[mi] = act + (size_t)(tka[mi] < 0 ? 0 : tka[mi]) * I_ + quad * 8;
        }

        f32x4 acc[4];
#pragma unroll
        for (int mi = 0; mi < 4; mi++) acc[mi] = (f32x4){0.f, 0.f, 0.f, 0.f};

        uint4 a0[4], a1[4];
        float4 d0[2], d1[2];

#define DN_LOAD(A, D, kk) do {                                                      \
        const int k_ = (kk);                                                        \
        _Pragma("unroll")                                                           \
        for (int mi = 0; mi < 4; mi++)                                              \
            A[mi] = (tka[mi] >= 0) ? *(const uint4*)(xa[mi] + k_)                   \
                                   : make_uint4(0u, 0u, 0u, 0u);                    \
        D[0] = *(const float4*)(dw + k_); D[1] = *(const float4*)(dw + k_ + 4);     \
    } while (0)

#define DN_MFMA(A, D) do {                                                          \
        bf16x8 bd = cvt8(D[0], D[1]);                                               \
        _Pragma("unroll")                                                           \
        for (int mi = 0; mi < 4; mi++) {                                            \
            bf16x8 aa = as_bf16x8(A[mi]);                                           \
            acc[mi] = __builtin_amdgcn_mfma_f32_16x16x32_bf16(aa, bd, acc[mi], 0, 0, 0); \
        }                                                                           \
    } while (0)

        DN_LOAD(a0, d0, 0);
#pragma unroll 1
        for (int k0 = 0; k0 < I_; k0 += 64) {
            DN_LOAD(a1, d1, k0 + 32);
            DN_MFMA(a0, d0);
            if (k0 + 64 < I_) DN_LOAD(a0, d0, k0 + 64);
            DN_MFMA(a1, d1);
        }
#undef DN_LOAD
#undef DN_MFMA

#pragma unroll
        for (int mi = 0; mi < 4; mi++)
#pragma unroll
            for (int r = 0; r < 4; r++) {
                int tok = toks[wv * 64 + mi * 16 + quad * 4 + r];
                if (tok < 0) continue;
                out[(size_t)tok * H_ + h0 + l15] = acc[mi][r];
            }
    }
}

extern "C" void kernel_launch(void* const* d_in, const int* in_sizes, int n_in,
                              void* d_out, int out_size, void* d_ws, size_t ws_size,
                              hipStream_t stream) {
    const float* hidden = (const float*)d_in[0];
    const float* rw     = (const float*)d_in[1];
    const float* gate_w = (const float*)d_in[2];
    const float* up_w   = (const float*)d_in[3];
    const float* down_w = (const float*)d_in[4];
    float* out = (float*)d_out;

    int* counts = (int*)d_ws;
    int* tlist  = counts + E_;
    ushort* xbf = (ushort*)(tlist + E_ * T_);          // 2 MB
    ushort* act = xbf + (size_t)T_ * H_;               // 5.77 MB

    hipMemsetAsync(counts, 0, E_ * sizeof(int), stream);
    hipLaunchKernelGGL(router_kernel, dim3(T_), dim3(64), 0, stream, hidden, rw, counts, tlist, xbf);
    hipLaunchKernelGGL(gateup_kernel, dim3(I_ / 32, E_), dim3(256), 0, stream,
                       xbf, gate_w, up_w, counts, tlist, act);
    hipLaunchKernelGGL(down_kernel, dim3(H_ / 16, E_), dim3(256), 0, stream,
                       act, down_w, counts, tlist, out);
}

// Round 2
// 382.912 us; speedup vs baseline: 1.1049x; 1.1049x over previous
//
#include <hip/hip_runtime.h>
#include <math.h>

// Problem dims (fixed)
constexpr int H_ = 1024;
constexpr int I_ = 2816;
constexpr int E_ = 8;
constexpr int T_ = 1024;   // S*B tokens

typedef __bf16 bf16x8 __attribute__((ext_vector_type(8)));
typedef float f32x4 __attribute__((ext_vector_type(4)));

__device__ __forceinline__ ushort f2bf(float f) {
    uint32_t u = __float_as_uint(f);
    u += 0x7fff + ((u >> 16) & 1);   // round-to-nearest-even
    return (ushort)(u >> 16);
}
__device__ __forceinline__ uint pack2(float lo, float hi) {
    return (uint)f2bf(lo) | ((uint)f2bf(hi) << 16);
}
__device__ __forceinline__ bf16x8 cvt8(float4 a, float4 b) {
    union { uint u[4]; bf16x8 v; } r;
    r.u[0] = pack2(a.x, a.y); r.u[1] = pack2(a.z, a.w);
    r.u[2] = pack2(b.x, b.y); r.u[3] = pack2(b.z, b.w);
    return r.v;
}

// async global->LDS, 16B per lane; LDS dest = wave-uniform base + lane*16 (HW).
__device__ __forceinline__ void async_copy16(void* lds, const void* g) {
    __builtin_amdgcn_global_load_lds(
        (const __attribute__((address_space(1))) void*)g,
        (__attribute__((address_space(3))) void*)lds, 16, 0, 0);
}

// LDS fragment readers with XOR swizzle (linear-dest global_load_lds => swizzle is
// applied on the SOURCE at stage time and again on the READ — same involution).
// A-tile: bf16 rows of 64B (BK=32). swizzle: byte ^= ((row>>1)&3)<<4  => <=2-way.
__device__ __forceinline__ bf16x8 ldsA(const ushort* base, int row, int quad) {
    int bir = (quad * 16) ^ (((row >> 1) & 3) << 4);
    return *(const bf16x8*)((const char*)base + row * 64 + bir);
}
// B-tile: fp32 rows of 128B (BK=32). swizzle: byte ^= (row&7)<<4  => 2-way (free).
__device__ __forceinline__ bf16x8 ldsB(const float* base, int row, int quad) {
    int sw = (row & 7) << 4;
    const char* r = (const char*)base + row * 128;
    float4 x = *(const float4*)(r + ((quad * 32) ^ sw));
    float4 y = *(const float4*)(r + ((quad * 32 + 16) ^ sw));
    return cvt8(x, y);
}

// ws layout: int counts[8]; int tlist[8*1024]; ushort xbf[1024*1024]; ushort act[1024*2816]

__global__ __launch_bounds__(64) void router_kernel(const float* __restrict__ hidden,
                                                    const float* __restrict__ rw,
                                                    int* __restrict__ counts,
                                                    int* __restrict__ tlist,
                                                    ushort* __restrict__ xbf) {
    const int t = blockIdx.x;
    const int lane = threadIdx.x;
    const float* x = hidden + (size_t)t * H_ + lane * 16;
    float4 v[4];
#pragma unroll
    for (int j = 0; j < 4; j++) v[j] = ((const float4*)x)[j];
    uint2* xb = (uint2*)(xbf + (size_t)t * H_ + lane * 16);
#pragma unroll
    for (int j = 0; j < 4; j++) xb[j] = make_uint2(pack2(v[j].x, v[j].y), pack2(v[j].z, v[j].w));
    float acc[E_];
#pragma unroll
    for (int e = 0; e < E_; e++) {
        const float4* r = (const float4*)(rw + e * H_ + lane * 16);
        float a = 0.f;
#pragma unroll
        for (int j = 0; j < 4; j++) {
            float4 rv = r[j];
            a += v[j].x * rv.x + v[j].y * rv.y + v[j].z * rv.z + v[j].w * rv.w;
        }
        acc[e] = a;
    }
#pragma unroll
    for (int e = 0; e < E_; e++) {
#pragma unroll
        for (int off = 32; off >= 1; off >>= 1)
            acc[e] += __shfl_xor(acc[e], off, 64);
    }
    if (lane == 0) {
        int best = 0;
        float bv = acc[0];
#pragma unroll
        for (int e = 1; e < E_; e++) {
            if (acc[e] > bv) { bv = acc[e]; best = e; }  // strict > : first max wins
        }
        int pos = atomicAdd(&counts[best], 1);
        tlist[best * T_ + pos] = t;
    }
}

// Phase A: per expert e, 32 I-rows, M=256 tokens, BK=32.
// global_load_lds double-buffered staging + counted vmcnt (never 0 in loop).
__global__ __launch_bounds__(256, 3) void gateup_kernel(const ushort* __restrict__ xbf,
                                                        const float* __restrict__ gate_w,
                                                        const float* __restrict__ up_w,
                                                        const int* __restrict__ counts,
                                                        const int* __restrict__ tlist,
                                                        ushort* __restrict__ act) {
    const int e  = blockIdx.y;
    const int i0 = blockIdx.x * 32;
    const int cnt = counts[e];
    const int tid = threadIdx.x;
    const int wv = tid >> 6, lane = tid & 63, quad = lane >> 4, l15 = lane & 15;

    __shared__ ushort Xs[2 * 256 * 32];   // 2 x 16KB, swizzled rows of 64B
    __shared__ float  Gs[2 * 32 * 32];    // 2 x 4KB, swizzled rows of 128B
    __shared__ float  Us[2 * 32 * 32];
    __shared__ int toks[256];

    // weight staging source (1 instr/thread/matrix): row=tid>>3, 16B chunk tid&7,
    // pre-swizzled column so linear LDS + swizzled read line up.
    const int wrow = tid >> 3;
    const int wbir = ((tid & 7) << 4) ^ ((wrow & 7) << 4);
    const float* gsrc = gate_w + ((size_t)e * I_ + i0 + wrow) * H_ + (wbir >> 2);
    const float* usrc = up_w   + ((size_t)e * I_ + i0 + wrow) * H_ + (wbir >> 2);

    for (int toff = 0; toff < cnt; toff += 256) {
        __syncthreads();
        { int p = toff + tid; toks[tid] = (p < cnt) ? tlist[e * T_ + p] : -1; }
        __syncthreads();

        // X staging sources: 4 instrs/thread, row = p*64 + tid/4, chunk tid&3.
        const ushort* xsrc[4];
#pragma unroll
        for (int p = 0; p < 4; p++) {
            int row = p * 64 + (tid >> 2);
            int tok = toks[row];
            if (tok < 0) tok = 0;   // garbage rows -> token 0 data; store is guarded
            int birl = ((tid & 3) << 4) ^ (((row >> 1) & 3) << 4);
            xsrc[p] = xbf + (size_t)tok * H_ + (birl >> 1);
        }

        f32x4 accg[4][2], accu[4][2];
#pragma unroll
        for (int mi = 0; mi < 4; mi++)
#pragma unroll
            for (int nj = 0; nj < 2; nj++) {
                accg[mi][nj] = (f32x4){0.f, 0.f, 0.f, 0.f};
                accu[mi][nj] = (f32x4){0.f, 0.f, 0.f, 0.f};
            }

#define GSTAGE(buf, kofs) do {                                                  \
        char* xb_ = (char*)Xs + (buf) * 16384 + wv * 1024;                      \
        _Pragma("unroll")                                                       \
        for (int p = 0; p < 4; p++)                                             \
            async_copy16(xb_ + p * 4096, xsrc[p] + (kofs));                     \
        async_copy16((char*)Gs + (buf) * 4096 + wv * 1024, gsrc + (kofs));      \
        async_copy16((char*)Us + (buf) * 4096 + wv * 1024, usrc + (kofs));      \
    } while (0)

        GSTAGE(0, 0);
        int cur = 0;
#pragma unroll 1
        for (int k0 = 0; k0 < H_; k0 += 32) {
            if (k0 + 32 < H_) {
                GSTAGE(cur ^ 1, k0 + 32);                       // 6 loads stay in flight
                asm volatile("s_waitcnt vmcnt(6)" ::: "memory"); // previous set complete
            } else {
                asm volatile("s_waitcnt vmcnt(0)" ::: "memory");
            }
            __builtin_amdgcn_s_barrier();
            __builtin_amdgcn_sched_barrier(0);

            const ushort* Xb = Xs + cur * 8192;
            const float*  Gb = Gs + cur * 1024;
            const float*  Ub = Us + cur * 1024;
            bf16x8 a[4], bg[2], bu[2];
#pragma unroll
            for (int nj = 0; nj < 2; nj++) {
                bg[nj] = ldsB(Gb, nj * 16 + l15, quad);
                bu[nj] = ldsB(Ub, nj * 16 + l15, quad);
            }
#pragma unroll
            for (int mi = 0; mi < 4; mi++)
                a[mi] = ldsA(Xb, wv * 64 + mi * 16 + l15, quad);
#pragma unroll
            for (int mi = 0; mi < 4; mi++)
#pragma unroll
                for (int nj = 0; nj < 2; nj++) {
                    accg[mi][nj] = __builtin_amdgcn_mfma_f32_16x16x32_bf16(a[mi], bg[nj], accg[mi][nj], 0, 0, 0);
                    accu[mi][nj] = __builtin_amdgcn_mfma_f32_16x16x32_bf16(a[mi], bu[nj], accu[mi][nj], 0, 0, 0);
                }
            __builtin_amdgcn_sched_barrier(0);
            __builtin_amdgcn_s_barrier();
            __builtin_amdgcn_sched_barrier(0);
            cur ^= 1;
        }
#undef GSTAGE

#pragma unroll
        for (int mi = 0; mi < 4; mi++)
#pragma unroll
            for (int r = 0; r < 4; r++) {
                int tok = toks[wv * 64 + mi * 16 + quad * 4 + r];
                if (tok < 0) continue;
#pragma unroll
                for (int nj = 0; nj < 2; nj++) {
                    float g = accg[mi][nj][r], u = accu[mi][nj][r];
                    float s = g / (1.f + __expf(-g)) * u;
                    act[(size_t)tok * I_ + i0 + nj * 16 + l15] = f2bf(s);
                }
            }
    }
}

// Phase B: per expert e, 16 H-rows, M=256 tokens, K=I=2816, BK=32, 3-deep pipeline.
__global__ __launch_bounds__(256, 2) void down_kernel(const ushort* __restrict__ act,
                                                      const float* __restrict__ down_w,
                                                      const int* __restrict__ counts,
                                                      const int* __restrict__ tlist,
                                                      float* __restrict__ out) {
    const int e  = blockIdx.y;
    const int h0 = blockIdx.x * 16;
    const int cnt = counts[e];
    const int tid = threadIdx.x;
    const int wv = tid >> 6, lane = tid & 63, quad = lane >> 4, l15 = lane & 15;

    __shared__ ushort As[3 * 256 * 32];   // 3 x 16KB
    __shared__ float  Ds[3 * 16 * 32];    // 3 x 2KB (staged by waves 0,1 only)
    __shared__ int toks[256];

    const int wrow = (tid >> 3) & 15;
    const int wbir = ((tid & 7) << 4) ^ ((wrow & 7) << 4);
    const float* dsrc = down_w + ((size_t)e * H_ + h0 + wrow) * I_ + (wbir >> 2);

    for (int toff = 0; toff < cnt; toff += 256) {
        __syncthreads();
        { int p = toff + tid; toks[tid] = (p < cnt) ? tlist[e * T_ + p] : -1; }
        __syncthreads();

        const ushort* asrc[4];
#pragma unroll
        for (int p = 0; p < 4; p++) {
            int row = p * 64 + (tid >> 2);
            int tok = toks[row];
            if (tok < 0) tok = 0;
            int birl = ((tid & 3) << 4) ^ (((row >> 1) & 3) << 4);
            asrc[p] = act + (size_t)tok * I_ + (birl >> 1);
        }

        f32x4 acc[4];
#pragma unroll
        for (int mi = 0; mi < 4; mi++) acc[mi] = (f32x4){0.f, 0.f, 0.f, 0.f};

#define DSTAGE(buf, kofs) do {                                                  \
        char* ab_ = (char*)As + (buf) * 16384 + wv * 1024;                      \
        _Pragma("unroll")                                                       \
        for (int p = 0; p < 4; p++)                                             \
            async_copy16(ab_ + p * 4096, asrc[p] + (kofs));                     \
        if (wv < 2)                                                             \
            async_copy16((char*)Ds + (buf) * 2048 + wv * 1024, dsrc + (kofs));  \
    } while (0)

        DSTAGE(0, 0);
        DSTAGE(1, 32);
        int cur = 0;
#pragma unroll 1
        for (int k0 = 0; k0 < I_; k0 += 32) {
            if (k0 + 64 < I_) {
                int stg = cur ? cur - 1 : 2;     // (t+2)%3
                DSTAGE(stg, k0 + 64);
                if (wv < 2) asm volatile("s_waitcnt vmcnt(10)" ::: "memory");
                else        asm volatile("s_waitcnt vmcnt(8)"  ::: "memory");
            } else if (k0 + 32 < I_) {
                if (wv < 2) asm volatile("s_waitcnt vmcnt(5)" ::: "memory");
                else        asm volatile("s_waitcnt vmcnt(4)" ::: "memory");
            } else {
                asm volatile("s_waitcnt vmcnt(0)" ::: "memory");
            }
            __builtin_amdgcn_s_barrier();
            __builtin_amdgcn_sched_barrier(0);

            const ushort* Ab = As + cur * 8192;
            const float*  Db = Ds + cur * 512;
            bf16x8 a[4];
            bf16x8 bd = ldsB(Db, l15, quad);
#pragma unroll
            for (int mi = 0; mi < 4; mi++)
                a[mi] = ldsA(Ab, wv * 64 + mi * 16 + l15, quad);
#pragma unroll
            for (int mi = 0; mi < 4; mi++)
                acc[mi] = __builtin_amdgcn_mfma_f32_16x16x32_bf16(a[mi], bd, acc[mi], 0, 0, 0);

            __builtin_amdgcn_sched_barrier(0);
            __builtin_amdgcn_s_barrier();
            __builtin_amdgcn_sched_barrier(0);
            cur = (cur == 2) ? 0 : cur + 1;
        }
#undef DSTAGE

#pragma unroll
        for (int mi = 0; mi < 4; mi++)
#pragma unroll
            for (int r = 0; r < 4; r++) {
                int tok = toks[wv * 64 + mi * 16 + quad * 4 + r];
                if (tok < 0) continue;
                out[(size_t)tok * H_ + h0 + l15] = acc[mi][r];
            }
    }
}

extern "C" void kernel_launch(void* const* d_in, const int* in_sizes, int n_in,
                              void* d_out, int out_size, void* d_ws, size_t ws_size,
                              hipStream_t stream) {
    const float* hidden = (const float*)d_in[0];
    const float* rw     = (const float*)d_in[1];
    const float* gate_w = (const float*)d_in[2];
    const float* up_w   = (const float*)d_in[3];
    const float* down_w = (const float*)d_in[4];
    float* out = (float*)d_out;

    int* counts = (int*)d_ws;
    int* tlist  = counts + E_;
    ushort* xbf = (ushort*)(tlist + E_ * T_);          // 2 MB
    ushort* act = xbf + (size_t)T_ * H_;               // 5.77 MB

    hipMemsetAsync(counts, 0, E_ * sizeof(int), stream);
    hipLaunchKernelGGL(router_kernel, dim3(T_), dim3(64), 0, stream, hidden, rw, counts, tlist, xbf);
    hipLaunchKernelGGL(gateup_kernel, dim3(I_ / 32, E_), dim3(256), 0, stream,
                       xbf, gate_w, up_w, counts, tlist, act);
    hipLaunchKernelGGL(down_kernel, dim3(H_ / 16, E_), dim3(256), 0, stream,
                       act, down_w, counts, tlist, out);
}

// Round 4
// 371.093 us; speedup vs baseline: 1.1401x; 1.0319x over previous
//
#include <hip/hip_runtime.h>
#include <math.h>

// Problem dims (fixed)
constexpr int H_ = 1024;
constexpr int I_ = 2816;
constexpr int E_ = 8;
constexpr int T_ = 1024;   // S*B tokens

typedef __bf16 bf16x8 __attribute__((ext_vector_type(8)));
typedef float f32x4 __attribute__((ext_vector_type(4)));

__device__ __forceinline__ ushort f2bf(float f) {
    uint32_t u = __float_as_uint(f);
    u += 0x7fff + ((u >> 16) & 1);   // round-to-nearest-even
    return (ushort)(u >> 16);
}
__device__ __forceinline__ uint pack2(float lo, float hi) {
    return (uint)f2bf(lo) | ((uint)f2bf(hi) << 16);
}
__device__ __forceinline__ bf16x8 as_bf16x8(uint4 v) {
    union { uint4 u; bf16x8 b; } c; c.u = v; return c.b;
}
// fp32x8 -> bf16x8 via v_cvt_pk_bf16_f32 (RNE, gfx950-verified T12 recipe).
__device__ __forceinline__ bf16x8 cvt8pk(float4 a, float4 b) {
    union { uint u[4]; bf16x8 v; } r;
    asm("v_cvt_pk_bf16_f32 %0, %1, %2" : "=v"(r.u[0]) : "v"(a.x), "v"(a.y));
    asm("v_cvt_pk_bf16_f32 %0, %1, %2" : "=v"(r.u[1]) : "v"(a.z), "v"(a.w));
    asm("v_cvt_pk_bf16_f32 %0, %1, %2" : "=v"(r.u[2]) : "v"(b.x), "v"(b.y));
    asm("v_cvt_pk_bf16_f32 %0, %1, %2" : "=v"(r.u[3]) : "v"(b.z), "v"(b.w));
    return r.v;
}

// async global->LDS, 16B per lane; LDS dest = wave-uniform base + lane*16 (HW).
__device__ __forceinline__ void async_copy16(void* lds, const void* g) {
    __builtin_amdgcn_global_load_lds(
        (const __attribute__((address_space(1))) void*)g,
        (__attribute__((address_space(3))) void*)lds, 16, 0, 0);
}

// ws layout: int counts[8]; int tlist[8*1024]; ushort xbf[1024*1024]; ushort act[1024*2816]

__global__ __launch_bounds__(64) void router_kernel(const float* __restrict__ hidden,
                                                    const float* __restrict__ rw,
                                                    int* __restrict__ counts,
                                                    int* __restrict__ tlist,
                                                    ushort* __restrict__ xbf) {
    const int t = blockIdx.x;
    const int lane = threadIdx.x;
    const float* x = hidden + (size_t)t * H_ + lane * 16;
    float4 v[4];
#pragma unroll
    for (int j = 0; j < 4; j++) v[j] = ((const float4*)x)[j];
    uint2* xb = (uint2*)(xbf + (size_t)t * H_ + lane * 16);
#pragma unroll
    for (int j = 0; j < 4; j++) xb[j] = make_uint2(pack2(v[j].x, v[j].y), pack2(v[j].z, v[j].w));
    float acc[E_];
#pragma unroll
    for (int e = 0; e < E_; e++) {
        const float4* r = (const float4*)(rw + e * H_ + lane * 16);
        float a = 0.f;
#pragma unroll
        for (int j = 0; j < 4; j++) {
            float4 rv = r[j];
            a += v[j].x * rv.x + v[j].y * rv.y + v[j].z * rv.z + v[j].w * rv.w;
        }
        acc[e] = a;
    }
#pragma unroll
    for (int e = 0; e < E_; e++) {
#pragma unroll
        for (int off = 32; off >= 1; off >>= 1)
            acc[e] += __shfl_xor(acc[e], off, 64);
    }
    if (lane == 0) {
        int best = 0;
        float bv = acc[0];
#pragma unroll
        for (int e = 1; e < E_; e++) {
            if (acc[e] > bv) { bv = acc[e]; best = e; }  // strict > : first max wins
        }
        int pos = atomicAdd(&counts[best], 1);
        tlist[best * T_ + pos] = t;
    }
}

// Phase A: per expert e, 32 I-rows, M=256 tokens, BK=32.
// A (tokens): direct global->register gather, 2-deep ping-pong (bf16, L2-resident).
// B (weights): global_load_lds into 4-deep buffers, staged 2 iters ahead,
// counted vmcnt(12), ONE barrier per iter. expert = blockIdx.x&7 -> XCD-local reuse.
__global__ __launch_bounds__(256, 3) void gateup_kernel(const ushort* __restrict__ xbf,
                                                        const float* __restrict__ gate_w,
                                                        const float* __restrict__ up_w,
                                                        const int* __restrict__ counts,
                                                        const int* __restrict__ tlist,
                                                        ushort* __restrict__ act) {
    const int id = blockIdx.x;
    const int e  = id & 7;              // all 88 blocks of an expert on one XCD
    const int i0 = (id >> 3) * 32;
    const int cnt = counts[e];
    const int tid = threadIdx.x;
    const int wv = tid >> 6, lane = tid & 63, quad = lane >> 4, l15 = lane & 15;

    __shared__ float Gs[4 * 1024];   // 4 bufs x 32 rows x 128B, chunk-XOR swizzled
    __shared__ float Us[4 * 1024];
    __shared__ int toks[256];

    // weight stage source: row=tid>>3 (32 rows), 16B chunk pre-swizzled by row&7
    const int wrow = tid >> 3;
    const int wcol = (((tid & 7) ^ (wrow & 7)) << 2);   // float offset
    const float* gsrc = gate_w + ((size_t)e * I_ + i0 + wrow) * H_ + wcol;
    const float* usrc = up_w   + ((size_t)e * I_ + i0 + wrow) * H_ + wcol;
    char* gdst = (char*)Gs + wv * 1024;
    char* udst = (char*)Us + wv * 1024;

#define STAGEW(buf, kofs) do {                                                  \
        async_copy16(gdst + (buf) * 4096, gsrc + (kofs));                       \
        async_copy16(udst + (buf) * 4096, usrc + (kofs));                       \
    } while (0)

    for (int toff = 0; toff < cnt; toff += 256) {
        __syncthreads();
        { int p = toff + tid; toks[tid] = (p < cnt) ? tlist[e * T_ + p] : -1; }
        __syncthreads();

        int tka[4]; const ushort* xa[4];
#pragma unroll
        for (int mi = 0; mi < 4; mi++) {
            tka[mi] = toks[wv * 64 + mi * 16 + l15];
            xa[mi] = xbf + (size_t)(tka[mi] < 0 ? 0 : tka[mi]) * H_ + quad * 8;
        }

        f32x4 accg[4][2], accu[4][2];
#pragma unroll
        for (int mi = 0; mi < 4; mi++)
#pragma unroll
            for (int nj = 0; nj < 2; nj++) {
                accg[mi][nj] = (f32x4){0.f, 0.f, 0.f, 0.f};
                accu[mi][nj] = (f32x4){0.f, 0.f, 0.f, 0.f};
            }

        uint4 xc[4], xn[4];
        STAGEW(0, 0);        // W(0)
        STAGEW(1, 32);       // W(1)
#pragma unroll
        for (int mi = 0; mi < 4; mi++) xc[mi] = *(const uint4*)(xa[mi]);   // X(0)

        // per iter t: issue X(t+1) [4 loads], stage W(t+2) [2]; wait W(t):
        // newer-than-W(t) = X(t)4 + W(t+1)2 + X(t+1)4 + W(t+2)2 = 12.
#define GBODY(k, XU, XL) do {                                                   \
        const int t_ = (k) >> 5;                                                \
        if ((k) + 32 < H_) {                                                    \
            _Pragma("unroll")                                                   \
            for (int mi = 0; mi < 4; mi++)                                      \
                XL[mi] = *(const uint4*)(xa[mi] + (k) + 32);                    \
        }                                                                       \
        __builtin_amdgcn_sched_barrier(0);                                      \
        if ((k) + 64 < H_) {                                                    \
            STAGEW((t_ + 2) & 3, (k) + 64);                                     \
            __builtin_amdgcn_sched_barrier(0);                                  \
            asm volatile("s_waitcnt vmcnt(12)" ::: "memory");                   \
        } else {                                                                \
            asm volatile("s_waitcnt vmcnt(0)" ::: "memory");                    \
        }                                                                       \
        __builtin_amdgcn_s_barrier();                                           \
        __builtin_amdgcn_sched_barrier(0);                                      \
        const float* Gb = Gs + (t_ & 3) * 1024;                                 \
        const float* Ub = Us + (t_ & 3) * 1024;                                 \
        bf16x8 bg[2], bu[2];                                                    \
        const int sw_ = (l15 & 7) << 4;                                         \
        _Pragma("unroll")                                                       \
        for (int nj = 0; nj < 2; nj++) {                                        \
            const char* gr = (const char*)Gb + (nj * 16 + l15) * 128;           \
            const char* ur = (const char*)Ub + (nj * 16 + l15) * 128;           \
            bg[nj] = cvt8pk(*(const float4*)(gr + ((quad * 32) ^ sw_)),         \
                            *(const float4*)(gr + ((quad * 32 + 16) ^ sw_)));   \
            bu[nj] = cvt8pk(*(const float4*)(ur + ((quad * 32) ^ sw_)),         \
                            *(const float4*)(ur + ((quad * 32 + 16) ^ sw_)));   \
        }                                                                       \
        _Pragma("unroll")                                                       \
        for (int mi = 0; mi < 4; mi++) {                                        \
            bf16x8 aa = as_bf16x8(XU[mi]);                                      \
            _Pragma("unroll")                                                   \
            for (int nj = 0; nj < 2; nj++) {                                    \
                accg[mi][nj] = __builtin_amdgcn_mfma_f32_16x16x32_bf16(aa, bg[nj], accg[mi][nj], 0, 0, 0); \
                accu[mi][nj] = __builtin_amdgcn_mfma_f32_16x16x32_bf16(aa, bu[nj], accu[mi][nj], 0, 0, 0); \
            }                                                                   \
        }                                                                       \
        __builtin_amdgcn_sched_barrier(0);                                      \
    } while (0)

#pragma unroll 1
        for (int k0 = 0; k0 < H_; k0 += 64) {
            GBODY(k0, xc, xn);
            GBODY(k0 + 32, xn, xc);
        }
#undef GBODY

#pragma unroll
        for (int mi = 0; mi < 4; mi++)
#pragma unroll
            for (int r = 0; r < 4; r++) {
                int tok = toks[wv * 64 + mi * 16 + quad * 4 + r];
                if (tok < 0) continue;
#pragma unroll
                for (int nj = 0; nj < 2; nj++) {
                    float g = accg[mi][nj][r], u = accu[mi][nj][r];
                    float s = g / (1.f + __expf(-g)) * u;
                    act[(size_t)tok * I_ + i0 + nj * 16 + l15] = f2bf(s);
                }
            }
    }
#undef STAGEW
}

// Phase B: per expert e, 16 H-rows, M=256 tokens, full K=I=2816, BK=64.
// A (act): direct global->register (XCD-local L2 via expert swizzle), ping-pong.
// B (weights): global_load_lds, 4-deep, counted vmcnt(18), one barrier/iter.
__global__ __launch_bounds__(256, 2) void down_kernel(const ushort* __restrict__ act,
                                                      const float* __restrict__ down_w,
                                                      const int* __restrict__ counts,
                                                      const int* __restrict__ tlist,
                                                      float* __restrict__ out) {
    const int id = blockIdx.x;
    const int e  = id & 7;              // 64 blocks of an expert share one XCD L2
    const int h0 = (id >> 3) * 16;
    const int cnt = counts[e];
    const int tid = threadIdx.x;
    const int wv = tid >> 6, lane = tid & 63, quad = lane >> 4, l15 = lane & 15;

    __shared__ float Ws[4 * 1024];   // 4 bufs x 16 rows x 256B, chunk-XOR swizzled
    __shared__ int toks[256];

    const int wrow = tid >> 4;                          // 16 rows, 16 thr each
    const int wcol = (((tid & 15) ^ (wrow & 7)) << 2);  // float offset (16B chunks)
    const float* dsrc = down_w + ((size_t)e * H_ + h0 + wrow) * I_ + wcol;
    char* ddst = (char*)Ws + wv * 1024;

#define STAGED(buf, kofs) async_copy16(ddst + (buf) * 4096, dsrc + (kofs))

    for (int toff = 0; toff < cnt; toff += 256) {
        __syncthreads();
        { int p = toff + tid; toks[tid] = (p < cnt) ? tlist[e * T_ + p] : -1; }
        __syncthreads();

        int tka[4]; const ushort* xa[4];
#pragma unroll
        for (int mi = 0; mi < 4; mi++) {
            tka[mi] = toks[wv * 64 + mi * 16 + l15];
            xa[mi] = act + (size_t)(tka[mi] < 0 ? 0 : tka[mi]) * I_ + quad * 8;
        }

        f32x4 acc[4];
#pragma unroll
        for (int mi = 0; mi < 4; mi++) acc[mi] = (f32x4){0.f, 0.f, 0.f, 0.f};

        uint4 ac[8], an[8];      // [mi*2 + half]
        STAGED(0, 0);            // W(0)
        STAGED(1, 64);           // W(1)
#pragma unroll
        for (int mi = 0; mi < 4; mi++) {
            ac[mi * 2 + 0] = *(const uint4*)(xa[mi]);
            ac[mi * 2 + 1] = *(const uint4*)(xa[mi] + 32);
        }

        // per iter t: issue A(t+1) [8 loads], stage W(t+2) [1]; wait W(t):
        // newer-than-W(t) = A(t)8 + W(t+1)1 + A(t+1)8 + W(t+2)1 = 18.
#define DBODY(k, AU, AL) do {                                                   \
        const int t_ = (k) >> 6;                                                \
        if ((k) + 64 < I_) {                                                    \
            _Pragma("unroll")                                                   \
            for (int mi = 0; mi < 4; mi++) {                                    \
                AL[mi * 2 + 0] = *(const uint4*)(xa[mi] + (k) + 64);            \
                AL[mi * 2 + 1] = *(const uint4*)(xa[mi] + (k) + 96);            \
            }                                                                   \
        }                                                                       \
        __builtin_amdgcn_sched_barrier(0);                                      \
        if ((k) + 128 < I_) {                                                   \
            STAGED((t_ + 2) & 3, (k) + 128);                                    \
            __builtin_amdgcn_sched_barrier(0);                                  \
            asm volatile("s_waitcnt vmcnt(18)" ::: "memory");                   \
        } else {                                                                \
            asm volatile("s_waitcnt vmcnt(0)" ::: "memory");                    \
        }                                                                       \
        __builtin_amdgcn_s_barrier();                                           \
        __builtin_amdgcn_sched_barrier(0);                                      \
        const char* Wb = (const char*)(Ws + (t_ & 3) * 1024) + l15 * 256;       \
        const int sw_ = (l15 & 7) << 4;                                         \
        _Pragma("unroll")                                                       \
        for (int h = 0; h < 2; h++) {                                           \
            bf16x8 bd = cvt8pk(                                                 \
                *(const float4*)(Wb + ((h * 128 + quad * 32) ^ sw_)),           \
                *(const float4*)(Wb + ((h * 128 + quad * 32 + 16) ^ sw_)));     \
            _Pragma("unroll")                                                   \
            for (int mi = 0; mi < 4; mi++)                                      \
                acc[mi] = __builtin_amdgcn_mfma_f32_16x16x32_bf16(              \
                    as_bf16x8(AU[mi * 2 + h]), bd, acc[mi], 0, 0, 0);           \
        }                                                                       \
        __builtin_amdgcn_sched_barrier(0);                                      \
    } while (0)

#pragma unroll 1
        for (int k0 = 0; k0 < I_; k0 += 128) {
            DBODY(k0, ac, an);
            DBODY(k0 + 64, an, ac);
        }
#undef DBODY

#pragma unroll
        for (int mi = 0; mi < 4; mi++)
#pragma unroll
            for (int r = 0; r < 4; r++) {
                int tok = toks[wv * 64 + mi * 16 + quad * 4 + r];
                if (tok < 0) continue;
                out[(size_t)tok * H_ + h0 + l15] = acc[mi][r];
            }
    }
#undef STAGED
}

extern "C" void kernel_launch(void* const* d_in, const int* in_sizes, int n_in,
                              void* d_out, int out_size, void* d_ws, size_t ws_size,
                              hipStream_t stream) {
    const float* hidden = (const float*)d_in[0];
    const float* rw     = (const float*)d_in[1];
    const float* gate_w = (const float*)d_in[2];
    const float* up_w   = (const float*)d_in[3];
    const float* down_w = (const float*)d_in[4];
    float* out = (float*)d_out;

    int* counts = (int*)d_ws;
    int* tlist  = counts + E_;
    ushort* xbf = (ushort*)(tlist + E_ * T_);          // 2 MB
    ushort* act = xbf + (size_t)T_ * H_;               // 5.77 MB

    hipMemsetAsync(counts, 0, E_ * sizeof(int), stream);
    hipLaunchKernelGGL(router_kernel, dim3(T_), dim3(64), 0, stream, hidden, rw, counts, tlist, xbf);
    hipLaunchKernelGGL(gateup_kernel, dim3((I_ / 32) * E_), dim3(256), 0, stream,
                       xbf, gate_w, up_w, counts, tlist, act);
    hipLaunchKernelGGL(down_kernel, dim3((H_ / 16) * E_), dim3(256), 0, stream,
                       act, down_w, counts, tlist, out);
}